// Round 2
// baseline (3976.006 us; speedup 1.0000x reference)
//
#include <hip/hip_runtime.h>
#include <hip/hip_bf16.h>

#define B_TOT 2048
#define NWIN  64
#define P     10
#define NTOK  59
#define C_DIM 384
#define HEADS 12
#define HD    32
#define NWTOK 49

#define AW_OFF 38535168   // x_out elems: 2048*49*384
#define PO_OFF 124096512  // + attn_weight elems: 2048*12*59*59

// ---------------------------------------------------------------------------
// Kernel 1: fused QKV (per-head slice of the GEMM) + attention.
// One block per (b, h). 256 threads.
// ---------------------------------------------------------------------------
__global__ __launch_bounds__(256) void qkv_attn_kernel(
    const float* __restrict__ x, const float* __restrict__ spa,
    const float* __restrict__ mask, const float* __restrict__ bias_table,
    const float* __restrict__ w_qkv, const float* __restrict__ b_qkv,
    float* __restrict__ aw_out, float* __restrict__ attn_out)
{
  const int blk = blockIdx.x;
  const int b = blk / HEADS;
  const int h = blk - b * HEADS;
  const int t = threadIdx.x;
  const int tr = t >> 4, tc = t & 15;

  __shared__ float xs[64][33];   // xc K-chunk tile (rows 59..63 unused garbage)
  __shared__ float ws[96][33];   // w_qkv head-slice K-chunk tile (q|k|v x 32)
  __shared__ float qs[NTOK][33];
  __shared__ float ks[NTOK][33];
  __shared__ float vs[NTOK][33];
  __shared__ float S[NTOK][60];

  float acc[4][6];
#pragma unroll
  for (int u = 0; u < 4; ++u)
#pragma unroll
    for (int m = 0; m < 6; ++m) acc[u][m] = 0.f;

  const int b0i = b >> 6;  // b / NWIN

  // ---- Phase 1: qkv_head = xc @ w_qkv_head^T, K tiled by 32 ----
  for (int k0 = 0; k0 < C_DIM; k0 += 32) {
    for (int e = t; e < NTOK * 8; e += 256) {
      const int r = e >> 3, q4 = (e & 7) * 4;
      const float* src = (r < P)
          ? (spa + ((size_t)(b0i * P + r)) * C_DIM + k0 + q4)
          : (x + ((size_t)(b * NWTOK + (r - P))) * C_DIM + k0 + q4);
      const float4 v4 = *(const float4*)src;
      xs[r][q4 + 0] = v4.x; xs[r][q4 + 1] = v4.y;
      xs[r][q4 + 2] = v4.z; xs[r][q4 + 3] = v4.w;
    }
    for (int e = t; e < 96 * 8; e += 256) {
      const int c = e >> 3, q4 = (e & 7) * 4;
      const int gr = (c >> 5) * C_DIM + h * HD + (c & 31);
      const float4 v4 = *(const float4*)(w_qkv + (size_t)gr * C_DIM + k0 + q4);
      ws[c][q4 + 0] = v4.x; ws[c][q4 + 1] = v4.y;
      ws[c][q4 + 2] = v4.z; ws[c][q4 + 3] = v4.w;
    }
    __syncthreads();
#pragma unroll 8
    for (int kk = 0; kk < 32; ++kk) {
      float a[4], bb[6];
#pragma unroll
      for (int u = 0; u < 4; ++u) a[u] = xs[tr + u * 16][kk];
#pragma unroll
      for (int m = 0; m < 6; ++m) bb[m] = ws[tc + m * 16][kk];
#pragma unroll
      for (int u = 0; u < 4; ++u)
#pragma unroll
        for (int m = 0; m < 6; ++m) acc[u][m] += a[u] * bb[m];
    }
    __syncthreads();
  }

  // scatter accumulators (+bias) into qs/ks/vs
#pragma unroll
  for (int u = 0; u < 4; ++u) {
    const int i = tr + u * 16;
    if (i < NTOK) {
#pragma unroll
      for (int m = 0; m < 6; ++m) {
        const int sec = m >> 1;              // 0=q 1=k 2=v
        const int d = tc + (m & 1) * 16;
        const float val = acc[u][m] + b_qkv[sec * C_DIM + h * HD + d];
        if (sec == 0) qs[i][d] = val;
        else if (sec == 1) ks[i][d] = val;
        else vs[i][d] = val;
      }
    }
  }
  __syncthreads();

  // ---- Phase 2: raw S = q k^T, written to attn_weight output + LDS ----
  float* aw = aw_out + (size_t)blk * (NTOK * NTOK);
  for (int idx = t; idx < NTOK * NTOK; idx += 256) {
    const int i = idx / NTOK, j = idx - i * NTOK;
    float s = 0.f;
#pragma unroll
    for (int d = 0; d < HD; ++d) s += qs[i][d] * ks[j][d];
    S[i][j] = s;
    aw[idx] = s;
  }
  __syncthreads();

  // ---- Phase 3: scale + bias + mask + softmax (one wave per row) ----
  const float scale = 0.17677669529663687f;
  const int wv = t >> 6, lane = t & 63;
  const int w = b & (NWIN - 1);
  for (int i = wv; i < NTOK; i += 4) {
    float val = -3.0e38f;
    if (lane < NTOK) {
      float s = S[i][lane] * scale;
      if (i >= P && lane >= P) {
        const int ti = i - P, tj = lane - P;
        const int ai = ti / 7, aj = ti - ai * 7;
        const int bi = tj / 7, bj = tj - bi * 7;
        const int ridx = (ai - bi + 6) * 13 + (aj - bj + 6);
        s += bias_table[ridx * HEADS + h];
        s += mask[((size_t)w * NWTOK + ti) * NWTOK + tj];
      }
      val = s;
    }
    float mx = val;
#pragma unroll
    for (int off = 32; off > 0; off >>= 1) mx = fmaxf(mx, __shfl_xor(mx, off));
    const float e = (lane < NTOK) ? __expf(val - mx) : 0.f;
    float sum = e;
#pragma unroll
    for (int off = 32; off > 0; off >>= 1) sum += __shfl_xor(sum, off);
    if (lane < NTOK) S[i][lane] = e / sum;
  }
  __syncthreads();

  // ---- Phase 4: O = P @ V -> attn_out[b][i][h*32+d] ----
  for (int idx = t; idx < NTOK * HD; idx += 256) {
    const int i = idx >> 5, d = idx & 31;
    float o = 0.f;
    for (int j = 0; j < NTOK; ++j) o += S[i][j] * vs[j][d];
    attn_out[((size_t)b * NTOK + i) * C_DIM + h * HD + d] = o;
  }
}

// ---------------------------------------------------------------------------
// Kernel 2: proj GEMM (120832 x 384) @ (384 x 384)^T + bias, routed outputs.
// BM=128 BN=64 BK=16, 256 threads, 8x4 per thread.
// ---------------------------------------------------------------------------
__global__ __launch_bounds__(256) void proj_kernel(
    const float* __restrict__ A, const float* __restrict__ w_proj,
    const float* __restrict__ b_proj, float* __restrict__ x_out,
    float* __restrict__ pbuf)
{
  __shared__ float As[16][136];
  __shared__ float Bs[16][72];
  const int c0 = blockIdx.x * 64;
  const int m0 = blockIdx.y * 128;
  const int t = threadIdx.x;
  const int tr = t >> 4, tc = t & 15;

  float acc[8][4];
#pragma unroll
  for (int u = 0; u < 8; ++u)
#pragma unroll
    for (int j = 0; j < 4; ++j) acc[u][j] = 0.f;

  for (int k0 = 0; k0 < C_DIM; k0 += 16) {
    for (int e = t; e < 512; e += 256) {
      const int r = e >> 2, q4 = (e & 3) * 4;
      const float4 v4 = *(const float4*)(A + (size_t)(m0 + r) * C_DIM + k0 + q4);
      As[q4 + 0][r] = v4.x; As[q4 + 1][r] = v4.y;
      As[q4 + 2][r] = v4.z; As[q4 + 3][r] = v4.w;
    }
    {
      const int e = t;
      if (e < 256) {
        const int c = e >> 2, q4 = (e & 3) * 4;
        const float4 v4 = *(const float4*)(w_proj + (size_t)(c0 + c) * C_DIM + k0 + q4);
        Bs[q4 + 0][c] = v4.x; Bs[q4 + 1][c] = v4.y;
        Bs[q4 + 2][c] = v4.z; Bs[q4 + 3][c] = v4.w;
      }
    }
    __syncthreads();
#pragma unroll
    for (int kk = 0; kk < 16; ++kk) {
      const float4 b4 = *(const float4*)&Bs[kk][tc * 4];
      const float4 a0 = *(const float4*)&As[kk][tr * 8];
      const float4 a1 = *(const float4*)&As[kk][tr * 8 + 4];
      const float a8[8] = {a0.x, a0.y, a0.z, a0.w, a1.x, a1.y, a1.z, a1.w};
#pragma unroll
      for (int u = 0; u < 8; ++u) {
        acc[u][0] += a8[u] * b4.x;
        acc[u][1] += a8[u] * b4.y;
        acc[u][2] += a8[u] * b4.z;
        acc[u][3] += a8[u] * b4.w;
      }
    }
    __syncthreads();
  }

  const float4 bias = *(const float4*)&b_proj[c0 + tc * 4];
#pragma unroll
  for (int u = 0; u < 8; ++u) {
    const int m = m0 + tr * 8 + u;
    const int bb = m / NTOK, n = m - bb * NTOK;
    float4 v;
    v.x = acc[u][0] + bias.x;
    v.y = acc[u][1] + bias.y;
    v.z = acc[u][2] + bias.z;
    v.w = acc[u][3] + bias.w;
    if (n >= P)
      *(float4*)(x_out + ((size_t)(bb * NWTOK + (n - P))) * C_DIM + c0 + tc * 4) = v;
    else
      *(float4*)(pbuf + ((size_t)(bb * P + n)) * C_DIM + c0 + tc * 4) = v;
  }
}

// ---------------------------------------------------------------------------
// Kernel 3: prompts_out = mean over 64 windows of pbuf
// ---------------------------------------------------------------------------
__global__ __launch_bounds__(256) void reduce_prompts_kernel(
    const float* __restrict__ pbuf, float* __restrict__ po)
{
  const int o = blockIdx.x * 256 + threadIdx.x;  // < 32*10*384
  const int b0 = o / 3840;
  const int rem = o - b0 * 3840;
  const float* base = pbuf + (size_t)b0 * 64 * 3840 + rem;
  float s = 0.f;
#pragma unroll 8
  for (int w = 0; w < 64; ++w) s += base[(size_t)w * 3840];
  po[o] = s * (1.f / 64.f);
}

extern "C" void kernel_launch(void* const* d_in, const int* in_sizes, int n_in,
                              void* d_out, int out_size, void* d_ws, size_t ws_size,
                              hipStream_t stream) {
  const float* x          = (const float*)d_in[0];
  const float* spa        = (const float*)d_in[1];
  const float* mask       = (const float*)d_in[2];
  const float* bias_table = (const float*)d_in[3];
  const float* w_qkv      = (const float*)d_in[4];
  const float* b_qkv      = (const float*)d_in[5];
  const float* w_proj     = (const float*)d_in[6];
  const float* b_proj     = (const float*)d_in[7];
  float* out = (float*)d_out;

  float* attn_out = (float*)d_ws;                       // 120832*384 floats
  float* pbuf = attn_out + (size_t)120832 * 384;        // 2048*10*384 floats

  qkv_attn_kernel<<<B_TOT * HEADS, 256, 0, stream>>>(
      x, spa, mask, bias_table, w_qkv, b_qkv, out + AW_OFF, attn_out);
  proj_kernel<<<dim3(6, 944), 256, 0, stream>>>(
      attn_out, w_proj, b_proj, out, pbuf);
  reduce_prompts_kernel<<<480, 256, 0, stream>>>(pbuf, out + PO_OFF);
}

// Round 3
// 1194.234 us; speedup vs baseline: 3.3293x; 3.3293x over previous
//
#include <hip/hip_runtime.h>
#include <hip/hip_bf16.h>

#define B_TOT 2048
#define NWIN  64
#define P     10
#define NTOK  59
#define C_DIM 384
#define HEADS 12
#define HD    32
#define NWTOK 49

#define AW_OFF 38535168   // x_out elems: 2048*49*384
#define PO_OFF 124096512  // + attn_weight elems (same as passing round-2 kernel)

typedef __attribute__((ext_vector_type(8))) short short8;
typedef __attribute__((ext_vector_type(8))) unsigned short ushort8;
typedef __attribute__((ext_vector_type(4))) float floatx4;

__device__ __forceinline__ unsigned short f2b(float f) {
  unsigned u = __builtin_bit_cast(unsigned, f);
  u += 0x7fffu + ((u >> 16) & 1u);
  return (unsigned short)(u >> 16);
}
__device__ __forceinline__ float b2f(unsigned short s) {
  return __builtin_bit_cast(float, ((unsigned)s) << 16);
}

// ---------------------------------------------------------------------------
// Kernel 0: convert w_qkv (1152x384 f32) -> bf16 once.
// ---------------------------------------------------------------------------
__global__ __launch_bounds__(256) void convert_w_kernel(
    const float* __restrict__ w, unsigned short* __restrict__ wb) {
  const int i = (blockIdx.x * 256 + threadIdx.x) * 8;  // 55296 threads * 8 = 442368
  const float4 a = *(const float4*)(w + i);
  const float4 b = *(const float4*)(w + i + 4);
  ushort8 o;
  o[0] = f2b(a.x); o[1] = f2b(a.y); o[2] = f2b(a.z); o[3] = f2b(a.w);
  o[4] = f2b(b.x); o[5] = f2b(b.y); o[6] = f2b(b.z); o[7] = f2b(b.w);
  *(ushort8*)(wb + i) = o;
}

// ---------------------------------------------------------------------------
// Kernel 1: fused QKV + attention, MFMA bf16. One block per (b,h), 4 waves.
// ---------------------------------------------------------------------------
__global__ __launch_bounds__(256) void qkv_attn_kernel(
    const float* __restrict__ x, const float* __restrict__ spa,
    const float* __restrict__ mask, const float* __restrict__ bias_table,
    const unsigned short* __restrict__ wqb, const float* __restrict__ b_qkv,
    float* __restrict__ aw_out, unsigned short* __restrict__ attn_bf)
{
  __shared__ char lds[40960];
  unsigned short* xs  = (unsigned short*)(lds);           // [64][72] bf16 (phase 1)
  unsigned short* wst = (unsigned short*)(lds + 9216);    // [96][72] bf16 (phase 1)
  float*          S   = (float*)(lds);                    // [64][66] f32  (phase 2+)
  unsigned short* Pm  = (unsigned short*)(lds + 16896);   // [64][72] bf16 (phase 3+)
  unsigned short* qs  = (unsigned short*)(lds + 26112);   // [64][40] bf16
  unsigned short* ks  = (unsigned short*)(lds + 31232);   // [64][40] bf16
  unsigned short* vt  = (unsigned short*)(lds + 36352);   // [32][72] bf16 (V transposed)

  const int blk = blockIdx.x;
  const int b = blk / HEADS;
  const int h = blk - b * HEADS;
  const int t = threadIdx.x;
  const int w = t >> 6, lane = t & 63;
  const int lr = lane & 15, lg = lane >> 4;
  const int w0 = w >> 1, w1 = w & 1;   // phase-1: wave = (m-half, n-half)
  const int b0i = b >> 6;

  floatx4 acc[2][3];
#pragma unroll
  for (int mt = 0; mt < 2; ++mt)
#pragma unroll
    for (int nt = 0; nt < 3; ++nt) acc[mt][nt] = (floatx4)0.f;

  // ---- Phase 1: qkv_head(64x96) = xc(64x384) @ Wslice(96x384)^T ----
  for (int k0 = 0; k0 < C_DIM; k0 += 64) {
    __syncthreads();
    // stage xc tile [64][64] bf16 (f32 global -> cvt), rows >=59 zero
    for (int e = t; e < 512; e += 256) {
      const int r = e >> 3, ch = e & 7;
      ushort8 o;
      if (r < NTOK) {
        const float* src = (r < P)
            ? spa + ((size_t)(b0i * P + r)) * C_DIM + k0 + ch * 8
            : x + ((size_t)(b * NWTOK + (r - P))) * C_DIM + k0 + ch * 8;
        const float4 v0 = ((const float4*)src)[0];
        const float4 v1 = ((const float4*)src)[1];
        o[0] = f2b(v0.x); o[1] = f2b(v0.y); o[2] = f2b(v0.z); o[3] = f2b(v0.w);
        o[4] = f2b(v1.x); o[5] = f2b(v1.y); o[6] = f2b(v1.z); o[7] = f2b(v1.w);
      } else {
        o = (ushort8)0;
      }
      *(ushort8*)(xs + r * 72 + ch * 8) = o;
    }
    // stage W slice [96][64] bf16 (rows: q0..31 | k0..31 | v0..31 of head h)
    for (int e = t; e < 768; e += 256) {
      const int r = e >> 3, ch = e & 7;
      const int grow = (r >> 5) * C_DIM + h * HD + (r & 31);
      *(ushort8*)(wst + r * 72 + ch * 8) =
          *(const ushort8*)(wqb + (size_t)grow * C_DIM + k0 + ch * 8);
    }
    __syncthreads();
#pragma unroll
    for (int kk = 0; kk < 2; ++kk) {
      short8 af[2], bfr[3];
#pragma unroll
      for (int mt = 0; mt < 2; ++mt)
        af[mt] = *(const short8*)(xs + (w0 * 32 + mt * 16 + lr) * 72 + kk * 32 + lg * 8);
#pragma unroll
      for (int nt = 0; nt < 3; ++nt)
        bfr[nt] = *(const short8*)(wst + (w1 * 48 + nt * 16 + lr) * 72 + kk * 32 + lg * 8);
#pragma unroll
      for (int mt = 0; mt < 2; ++mt)
#pragma unroll
        for (int nt = 0; nt < 3; ++nt)
          acc[mt][nt] = __builtin_amdgcn_mfma_f32_16x16x32_bf16(
              af[mt], bfr[nt], acc[mt][nt], 0, 0, 0);
    }
  }

  // scatter C-frags (+bias) -> qs / ks / vt (bf16)
#pragma unroll
  for (int nt = 0; nt < 3; ++nt) {
    const int ntg = w1 * 3 + nt;
    const int sec = ntg >> 1;                // 0=q 1=k 2=v
    const int d = (ntg & 1) * 16 + lr;
    const float bias = b_qkv[sec * C_DIM + h * HD + d];
#pragma unroll
    for (int mt = 0; mt < 2; ++mt) {
#pragma unroll
      for (int reg = 0; reg < 4; ++reg) {
        const int row = w0 * 32 + mt * 16 + lg * 4 + reg;
        const unsigned short bv = f2b(acc[mt][nt][reg] + bias);
        if (sec == 0)      qs[row * 40 + d] = bv;
        else if (sec == 1) ks[row * 40 + d] = bv;
        else               vt[d * 72 + row] = bv;
      }
    }
  }
  __syncthreads();

  // ---- Phase 2: S = q k^T (wave w owns rows w*16..w*16+15) ----
  const short8 qa = *(const short8*)(qs + (w * 16 + lr) * 40 + lg * 8);
  floatx4 sacc[4];
#pragma unroll
  for (int nt = 0; nt < 4; ++nt) {
    sacc[nt] = (floatx4)0.f;
    const short8 kb = *(const short8*)(ks + (nt * 16 + lr) * 40 + lg * 8);
    sacc[nt] = __builtin_amdgcn_mfma_f32_16x16x32_bf16(qa, kb, sacc[nt], 0, 0, 0);
  }
  float* aw = aw_out + (size_t)blk * (NTOK * NTOK);
#pragma unroll
  for (int nt = 0; nt < 4; ++nt)
#pragma unroll
    for (int reg = 0; reg < 4; ++reg) {
      const int row = w * 16 + lg * 4 + reg;
      const int col = nt * 16 + lr;
      S[row * 66 + col] = sacc[nt][reg];
      if (row < NTOK && col < NTOK) aw[row * NTOK + col] = sacc[nt][reg];
    }

  // ---- Phase 3: softmax (wave-local rows), P -> bf16 LDS ----
  const float scale = 0.17677669529663687f;
  const int wnd = b & (NWIN - 1);
  for (int i = 0; i < 16; ++i) {
    const int row = w * 16 + i;
    if (row >= NTOK) break;
    float val = -3.0e38f;
    if (lane < NTOK) {
      float s = S[row * 66 + lane] * scale;
      if (row >= P && lane >= P) {
        const int ti = row - P, tj = lane - P;
        const int ai = ti / 7, aj = ti - ai * 7;
        const int bi = tj / 7, bj = tj - bi * 7;
        const int ridx = (ai - bi + 6) * 13 + (aj - bj + 6);
        s += bias_table[ridx * HEADS + h];
        s += mask[((size_t)wnd * NWTOK + ti) * NWTOK + tj];
      }
      val = s;
    }
    float mx = val;
#pragma unroll
    for (int off = 32; off > 0; off >>= 1) mx = fmaxf(mx, __shfl_xor(mx, off));
    const float e = (lane < NTOK) ? __expf(val - mx) : 0.f;
    float sm = e;
#pragma unroll
    for (int off = 32; off > 0; off >>= 1) sm += __shfl_xor(sm, off);
    Pm[row * 72 + lane] = f2b(e / sm);   // lanes 59..63 write exact 0
  }

  // ---- Phase 4: O = P @ V ----
  floatx4 oacc[2];
  oacc[0] = (floatx4)0.f; oacc[1] = (floatx4)0.f;
#pragma unroll
  for (int kk = 0; kk < 2; ++kk) {
    const short8 pa = *(const short8*)(Pm + (w * 16 + lr) * 72 + kk * 32 + lg * 8);
#pragma unroll
    for (int nt = 0; nt < 2; ++nt) {
      const short8 vb = *(const short8*)(vt + (nt * 16 + lr) * 72 + kk * 32 + lg * 8);
      oacc[nt] = __builtin_amdgcn_mfma_f32_16x16x32_bf16(pa, vb, oacc[nt], 0, 0, 0);
    }
  }
#pragma unroll
  for (int nt = 0; nt < 2; ++nt)
#pragma unroll
    for (int reg = 0; reg < 4; ++reg) {
      const int row = w * 16 + lg * 4 + reg;
      if (row < NTOK) {
        const int d = nt * 16 + lr;
        attn_bf[((size_t)(b * NTOK + row)) * C_DIM + h * HD + d] = f2b(oacc[nt][reg]);
      }
    }
}

// ---------------------------------------------------------------------------
// Kernel 2: proj GEMM (120832 x 384) @ (384 x 384)^T + bias. A is bf16.
// ---------------------------------------------------------------------------
__global__ __launch_bounds__(256) void proj_kernel(
    const unsigned short* __restrict__ A, const float* __restrict__ w_proj,
    const float* __restrict__ b_proj, float* __restrict__ x_out,
    float* __restrict__ pbuf)
{
  __shared__ float As[16][136];
  __shared__ float Bs[16][72];
  const int c0 = blockIdx.x * 64;
  const int m0 = blockIdx.y * 128;
  const int t = threadIdx.x;
  const int tr = t >> 4, tc = t & 15;

  float acc[8][4];
#pragma unroll
  for (int u = 0; u < 8; ++u)
#pragma unroll
    for (int j = 0; j < 4; ++j) acc[u][j] = 0.f;

  for (int k0 = 0; k0 < C_DIM; k0 += 16) {
    {
      const int r = t >> 1, c8 = (t & 1) * 8;
      const ushort8 v = *(const ushort8*)(A + (size_t)(m0 + r) * C_DIM + k0 + c8);
#pragma unroll
      for (int j = 0; j < 8; ++j) As[c8 + j][r] = b2f(v[j]);
    }
    if (t < 256) {
      const int c = t >> 2, q4 = (t & 3) * 4;
      const float4 v4 = *(const float4*)(w_proj + (size_t)(c0 + c) * C_DIM + k0 + q4);
      Bs[q4 + 0][c] = v4.x; Bs[q4 + 1][c] = v4.y;
      Bs[q4 + 2][c] = v4.z; Bs[q4 + 3][c] = v4.w;
    }
    __syncthreads();
#pragma unroll
    for (int kk = 0; kk < 16; ++kk) {
      const float4 b4 = *(const float4*)&Bs[kk][tc * 4];
      const float4 a0 = *(const float4*)&As[kk][tr * 8];
      const float4 a1 = *(const float4*)&As[kk][tr * 8 + 4];
      const float a8[8] = {a0.x, a0.y, a0.z, a0.w, a1.x, a1.y, a1.z, a1.w};
#pragma unroll
      for (int u = 0; u < 8; ++u) {
        acc[u][0] += a8[u] * b4.x;
        acc[u][1] += a8[u] * b4.y;
        acc[u][2] += a8[u] * b4.z;
        acc[u][3] += a8[u] * b4.w;
      }
    }
    __syncthreads();
  }

  const float4 bias = *(const float4*)&b_proj[c0 + tc * 4];
#pragma unroll
  for (int u = 0; u < 8; ++u) {
    const int m = m0 + tr * 8 + u;
    const int bb = m / NTOK, n = m - bb * NTOK;
    float4 v;
    v.x = acc[u][0] + bias.x;
    v.y = acc[u][1] + bias.y;
    v.z = acc[u][2] + bias.z;
    v.w = acc[u][3] + bias.w;
    if (n >= P)
      *(float4*)(x_out + ((size_t)(bb * NWTOK + (n - P))) * C_DIM + c0 + tc * 4) = v;
    else
      *(float4*)(pbuf + ((size_t)(bb * P + n)) * C_DIM + c0 + tc * 4) = v;
  }
}

// ---------------------------------------------------------------------------
// Kernel 3: prompts_out = mean over 64 windows
// ---------------------------------------------------------------------------
__global__ __launch_bounds__(256) void reduce_prompts_kernel(
    const float* __restrict__ pbuf, float* __restrict__ po)
{
  const int o = blockIdx.x * 256 + threadIdx.x;  // < 32*10*384
  const int b0 = o / 3840;
  const int rem = o - b0 * 3840;
  const float* base = pbuf + (size_t)b0 * 64 * 3840 + rem;
  float s = 0.f;
#pragma unroll 8
  for (int w = 0; w < 64; ++w) s += base[(size_t)w * 3840];
  po[o] = s * (1.f / 64.f);
}

extern "C" void kernel_launch(void* const* d_in, const int* in_sizes, int n_in,
                              void* d_out, int out_size, void* d_ws, size_t ws_size,
                              hipStream_t stream) {
  const float* x          = (const float*)d_in[0];
  const float* spa        = (const float*)d_in[1];
  const float* mask       = (const float*)d_in[2];
  const float* bias_table = (const float*)d_in[3];
  const float* w_qkv      = (const float*)d_in[4];
  const float* b_qkv      = (const float*)d_in[5];
  const float* w_proj     = (const float*)d_in[6];
  const float* b_proj     = (const float*)d_in[7];
  float* out = (float*)d_out;

  // ws: attn_bf (bf16, 120832*384) | wqb (bf16, 1152*384) | pbuf (f32, 2048*10*384)
  unsigned short* attn_bf = (unsigned short*)d_ws;
  unsigned short* wqb = (unsigned short*)((char*)d_ws + 92798976);
  float* pbuf = (float*)((char*)d_ws + 92798976 + 884736);

  convert_w_kernel<<<216, 256, 0, stream>>>(w_qkv, wqb);
  qkv_attn_kernel<<<B_TOT * HEADS, 256, 0, stream>>>(
      x, spa, mask, bias_table, wqb, b_qkv, out + AW_OFF, attn_bf);
  proj_kernel<<<dim3(6, 944), 256, 0, stream>>>(
      attn_bf, w_proj, b_proj, out, pbuf);
  reduce_prompts_kernel<<<480, 256, 0, stream>>>(pbuf, out + PO_OFF);
}

// Round 4
// 720.961 us; speedup vs baseline: 5.5149x; 1.6564x over previous
//
#include <hip/hip_runtime.h>
#include <hip/hip_bf16.h>

#define P     10
#define NTOK  59
#define HEADS 12
#define NWTOK 49

#define AW_OFF 38535168   // x_out elems: 2048*49*384
#define PO_OFF 124096512  // + attn_weight elems

typedef __attribute__((ext_vector_type(8))) short short8;
typedef __attribute__((ext_vector_type(8))) unsigned short ushort8;
typedef __attribute__((ext_vector_type(4))) float floatx4;
typedef unsigned int uint_g __attribute__((address_space(1)));
typedef unsigned int uint_l __attribute__((address_space(3)));

__device__ __forceinline__ unsigned short f2b(float f) {
  unsigned u = __builtin_bit_cast(unsigned, f);
  u += 0x7fffu + ((u >> 16) & 1u);
  return (unsigned short)(u >> 16);
}

__device__ __forceinline__ void gll16(const void* g, void* l) {
  __builtin_amdgcn_global_load_lds((const uint_g*)g, (uint_l*)l, 16, 0, 0);
}

// ---------------------------------------------------------------------------
// convert f32 -> bf16 flat (grid sized exactly: n/8/256 blocks)
// ---------------------------------------------------------------------------
__global__ __launch_bounds__(256) void convert_w_kernel(
    const float* __restrict__ w, unsigned short* __restrict__ wb) {
  const int i = (blockIdx.x * 256 + threadIdx.x) * 8;
  const float4 a = *(const float4*)(w + i);
  const float4 b = *(const float4*)(w + i + 4);
  ushort8 o;
  o[0] = f2b(a.x); o[1] = f2b(a.y); o[2] = f2b(a.z); o[3] = f2b(a.w);
  o[4] = f2b(b.x); o[5] = f2b(b.y); o[6] = f2b(b.z); o[7] = f2b(b.w);
  *(ushort8*)(wb + i) = o;
}

// ---------------------------------------------------------------------------
// gather xc (prompt-broadcast + x) -> bf16 [120832][384]
// ---------------------------------------------------------------------------
__global__ __launch_bounds__(256) void gather_x_kernel(
    const float* __restrict__ x, const float* __restrict__ spa,
    unsigned short* __restrict__ xc) {
  const int chunk = blockIdx.x * 256 + threadIdx.x;   // 5,799,936 total
  const int m = chunk / 48, kc = chunk - m * 48;
  const int b = m / 59, tok = m - b * 59;
  const float* src = (tok < P)
      ? spa + ((size_t)((b >> 6) * P + tok)) * 384 + kc * 8
      : x + ((size_t)(b * NWTOK + tok - P)) * 384 + kc * 8;
  const float4 v0 = ((const float4*)src)[0];
  const float4 v1 = ((const float4*)src)[1];
  ushort8 o;
  o[0] = f2b(v0.x); o[1] = f2b(v0.y); o[2] = f2b(v0.z); o[3] = f2b(v0.w);
  o[4] = f2b(v1.x); o[5] = f2b(v1.y); o[6] = f2b(v1.z); o[7] = f2b(v1.w);
  *(ushort8*)(xc + (size_t)m * 384 + kc * 8) = o;
}

// ---------------------------------------------------------------------------
// QKV GEMM: [120832][1152] = xc_bf @ wqkv_bf^T (+bias), bf16 out in
// per-(b,sec,head) [59][32] chunks. BM=BN=128, BK=64, 4 waves.
// global_load_lds with XOR-swizzled per-lane source; swizzled ds_read.
// ---------------------------------------------------------------------------
__global__ __launch_bounds__(256) void gemm_qkv_kernel(
    const unsigned short* __restrict__ A, const unsigned short* __restrict__ Bw,
    const float* __restrict__ b_qkv, unsigned short* __restrict__ qkvw) {
  __shared__ unsigned short Asw[8192];   // [128 rows][64 k], 128B/row, swizzled
  __shared__ unsigned short Bsw[8192];
  const int t = threadIdx.x;
  const int w = t >> 6, lane = t & 63;
  const int lr = lane & 15, lg = lane >> 4;
  const int w0 = w >> 1, w1 = w & 1;
  const size_t m0 = (size_t)blockIdx.y * 128;
  const int n0 = blockIdx.x * 128;
  const int srow = lane >> 3, cpos = lane & 7;

  floatx4 acc[4][4];
#pragma unroll
  for (int mr = 0; mr < 4; ++mr)
#pragma unroll
    for (int nc = 0; nc < 4; ++nc) acc[mr][nc] = (floatx4)0.f;

  for (int k0 = 0; k0 < 384; k0 += 64) {
#pragma unroll
    for (int i = 0; i < 4; ++i) {
      const int r = (w * 4 + i) * 8 + srow;         // 0..127
      const int c = cpos ^ (r & 7);                 // logical chunk fetched
      gll16(A + (m0 + r) * 384 + k0 + c * 8, Asw + (w * 4 + i) * 512);
      gll16(Bw + (size_t)(n0 + r) * 384 + k0 + c * 8, Bsw + (w * 4 + i) * 512);
    }
    __syncthreads();
#pragma unroll
    for (int kh = 0; kh < 2; ++kh) {
      short8 af[4], bf[4];
#pragma unroll
      for (int mr = 0; mr < 4; ++mr) {
        const int r = w0 * 64 + mr * 16 + lr;
        af[mr] = *(const short8*)(Asw + r * 64 + (((kh * 4 + lg) ^ (r & 7)) * 8));
      }
#pragma unroll
      for (int nc = 0; nc < 4; ++nc) {
        const int r = w1 * 64 + nc * 16 + lr;
        bf[nc] = *(const short8*)(Bsw + r * 64 + (((kh * 4 + lg) ^ (r & 7)) * 8));
      }
#pragma unroll
      for (int mr = 0; mr < 4; ++mr)
#pragma unroll
        for (int nc = 0; nc < 4; ++nc)
          acc[mr][nc] = __builtin_amdgcn_mfma_f32_16x16x32_bf16(
              af[mr], bf[nc], acc[mr][nc], 0, 0, 0);
    }
    __syncthreads();
  }

  // epilogue: +bias, f2b, scatter to qkvw[(b*3+sec)*12+h][tok][d]
  const int sec = blockIdx.x / 3;
  float bias[4]; int hh[4], dd[4];
#pragma unroll
  for (int nc = 0; nc < 4; ++nc) {
    const int n = n0 + w1 * 64 + nc * 16 + lr;
    bias[nc] = b_qkv[n];
    hh[nc] = (n >> 5) % 12;
    dd[nc] = n & 31;
  }
#pragma unroll
  for (int mr = 0; mr < 4; ++mr)
#pragma unroll
    for (int reg = 0; reg < 4; ++reg) {
      const int m = (int)m0 + w0 * 64 + mr * 16 + lg * 4 + reg;
      const int bb = m / 59, tok = m - bb * 59;
      const size_t base = (size_t)(bb * 3 + sec) * 12 * 1888 + (size_t)tok * 32;
#pragma unroll
      for (int nc = 0; nc < 4; ++nc)
        qkvw[base + (size_t)hh[nc] * 1888 + dd[nc]] =
            f2b(acc[mr][nc][reg] + bias[nc]);
    }
}

// ---------------------------------------------------------------------------
// attention: per (b,h), 4 waves. Stage q/k/v (11 KB) -> S (MFMA) -> aw ->
// softmax -> PV -> attn_bf.
// ---------------------------------------------------------------------------
__global__ __launch_bounds__(256) void attn_kernel(
    const unsigned short* __restrict__ qkvw, const float* __restrict__ mask,
    const float* __restrict__ bias_table, float* __restrict__ aw_out,
    unsigned short* __restrict__ attn_bf) {
  __shared__ char lds[31744];
  float* S = (float*)lds;                               // [64][66] f32
  unsigned short* qs = (unsigned short*)(lds + 16896);  // [64][40]
  unsigned short* ks = (unsigned short*)(lds + 22016);  // [64][40]
  unsigned short* vt = (unsigned short*)(lds + 27136);  // [32][72] (V^T)
  unsigned short* Pm = (unsigned short*)(lds + 16896);  // [64][72] alias qs/ks

  const int blk = blockIdx.x;
  const int b = blk / HEADS, h = blk - b * HEADS;
  const int t = threadIdx.x;
  const int w = t >> 6, lane = t & 63, lr = lane & 15, lg = lane >> 4;

  const size_t qoff = ((size_t)(b * 3 + 0) * 12 + h) * 1888;
  const size_t koff = ((size_t)(b * 3 + 1) * 12 + h) * 1888;
  const size_t voff = ((size_t)(b * 3 + 2) * 12 + h) * 1888;

  if (t < 236) {
    const int row = t >> 2, dc = (t & 3) * 8;
    const ushort8 q8 = *(const ushort8*)(qkvw + qoff + t * 8);
    const ushort8 k8 = *(const ushort8*)(qkvw + koff + t * 8);
    const ushort8 v8 = *(const ushort8*)(qkvw + voff + t * 8);
    *(ushort8*)(qs + row * 40 + dc) = q8;
    *(ushort8*)(ks + row * 40 + dc) = k8;
#pragma unroll
    for (int j = 0; j < 8; ++j) vt[(dc + j) * 72 + row] = v8[j];
  } else {
    const int e = t - 236;  // zero vt token cols 59..63
#pragma unroll
    for (int jj = 0; jj < 8; ++jj) {
      const int f = e * 8 + jj;  // 0..159
      vt[(f / 5) * 72 + 59 + (f % 5)] = 0;
    }
  }
  __syncthreads();

  // S = q k^T (wave w owns rows w*16..w*16+15)
  const short8 qa = *(const short8*)(qs + (w * 16 + lr) * 40 + lg * 8);
  floatx4 sacc[4];
#pragma unroll
  for (int nt = 0; nt < 4; ++nt) {
    const short8 kb = *(const short8*)(ks + (nt * 16 + lr) * 40 + lg * 8);
    sacc[nt] = __builtin_amdgcn_mfma_f32_16x16x32_bf16(qa, kb, (floatx4)0.f, 0, 0, 0);
  }
  float* aw = aw_out + (size_t)blk * (NTOK * NTOK);
#pragma unroll
  for (int nt = 0; nt < 4; ++nt)
#pragma unroll
    for (int reg = 0; reg < 4; ++reg) {
      const int row = w * 16 + lg * 4 + reg;
      const int col = nt * 16 + lr;
      S[row * 66 + col] = sacc[nt][reg];
      if (row < NTOK && col < NTOK) aw[row * NTOK + col] = sacc[nt][reg];
    }
  __syncthreads();

  // softmax rows (wave-local), P -> bf16 Pm
  const float scale = 0.17677669529663687f;
  const int wnd = b & 63;
  for (int i = 0; i < 16; ++i) {
    const int row = w * 16 + i;
    if (row >= NTOK) break;
    float val = -3.0e38f;
    if (lane < NTOK) {
      float s = S[row * 66 + lane] * scale;
      if (row >= P && lane >= P) {
        const int ti = row - P, tj = lane - P;
        const int ai = ti / 7, aj = ti - ai * 7;
        const int bi = tj / 7, bj = tj - bi * 7;
        const int ridx = (ai - bi + 6) * 13 + (aj - bj + 6);
        s += bias_table[ridx * HEADS + h];
        s += mask[((size_t)wnd * NWTOK + ti) * NWTOK + tj];
      }
      val = s;
    }
    float mx = val;
#pragma unroll
    for (int off = 32; off > 0; off >>= 1) mx = fmaxf(mx, __shfl_xor(mx, off));
    const float e = (lane < NTOK) ? __expf(val - mx) : 0.f;
    float sm = e;
#pragma unroll
    for (int off = 32; off > 0; off >>= 1) sm += __shfl_xor(sm, off);
    Pm[row * 72 + lane] = f2b(e / sm);   // lanes 59..63 exact 0
  }

  // O = P @ V (wave-local rows; Pm/vt deps are wave-local -> no barrier)
  floatx4 oacc[2];
  oacc[0] = (floatx4)0.f; oacc[1] = (floatx4)0.f;
#pragma unroll
  for (int kk = 0; kk < 2; ++kk) {
    const short8 pa = *(const short8*)(Pm + (w * 16 + lr) * 72 + kk * 32 + lg * 8);
#pragma unroll
    for (int nt = 0; nt < 2; ++nt) {
      const short8 vb = *(const short8*)(vt + (nt * 16 + lr) * 72 + kk * 32 + lg * 8);
      oacc[nt] = __builtin_amdgcn_mfma_f32_16x16x32_bf16(pa, vb, oacc[nt], 0, 0, 0);
    }
  }
#pragma unroll
  for (int nt = 0; nt < 2; ++nt)
#pragma unroll
    for (int reg = 0; reg < 4; ++reg) {
      const int row = w * 16 + lg * 4 + reg;
      if (row < NTOK) {
        const int d = nt * 16 + lr;
        attn_bf[((size_t)(b * NTOK + row)) * 384 + h * 32 + d] = f2b(oacc[nt][reg]);
      }
    }
}

// ---------------------------------------------------------------------------
// proj GEMM: [120832][384] = attn_bf @ wproj_bf^T (+bias), f32 routed out.
// Same structure as gemm_qkv.
// ---------------------------------------------------------------------------
__global__ __launch_bounds__(256) void gemm_proj_kernel(
    const unsigned short* __restrict__ A, const unsigned short* __restrict__ Bw,
    const float* __restrict__ b_proj, float* __restrict__ x_out,
    float* __restrict__ pbuf) {
  __shared__ unsigned short Asw[8192];
  __shared__ unsigned short Bsw[8192];
  const int t = threadIdx.x;
  const int w = t >> 6, lane = t & 63;
  const int lr = lane & 15, lg = lane >> 4;
  const int w0 = w >> 1, w1 = w & 1;
  const size_t m0 = (size_t)blockIdx.y * 128;
  const int n0 = blockIdx.x * 128;
  const int srow = lane >> 3, cpos = lane & 7;

  floatx4 acc[4][4];
#pragma unroll
  for (int mr = 0; mr < 4; ++mr)
#pragma unroll
    for (int nc = 0; nc < 4; ++nc) acc[mr][nc] = (floatx4)0.f;

  for (int k0 = 0; k0 < 384; k0 += 64) {
#pragma unroll
    for (int i = 0; i < 4; ++i) {
      const int r = (w * 4 + i) * 8 + srow;
      const int c = cpos ^ (r & 7);
      gll16(A + (m0 + r) * 384 + k0 + c * 8, Asw + (w * 4 + i) * 512);
      gll16(Bw + (size_t)(n0 + r) * 384 + k0 + c * 8, Bsw + (w * 4 + i) * 512);
    }
    __syncthreads();
#pragma unroll
    for (int kh = 0; kh < 2; ++kh) {
      short8 af[4], bf[4];
#pragma unroll
      for (int mr = 0; mr < 4; ++mr) {
        const int r = w0 * 64 + mr * 16 + lr;
        af[mr] = *(const short8*)(Asw + r * 64 + (((kh * 4 + lg) ^ (r & 7)) * 8));
      }
#pragma unroll
      for (int nc = 0; nc < 4; ++nc) {
        const int r = w1 * 64 + nc * 16 + lr;
        bf[nc] = *(const short8*)(Bsw + r * 64 + (((kh * 4 + lg) ^ (r & 7)) * 8));
      }
#pragma unroll
      for (int mr = 0; mr < 4; ++mr)
#pragma unroll
        for (int nc = 0; nc < 4; ++nc)
          acc[mr][nc] = __builtin_amdgcn_mfma_f32_16x16x32_bf16(
              af[mr], bf[nc], acc[mr][nc], 0, 0, 0);
    }
    __syncthreads();
  }

  float bias[4]; int nn[4];
#pragma unroll
  for (int nc = 0; nc < 4; ++nc) {
    nn[nc] = n0 + w1 * 64 + nc * 16 + lr;
    bias[nc] = b_proj[nn[nc]];
  }
#pragma unroll
  for (int mr = 0; mr < 4; ++mr)
#pragma unroll
    for (int reg = 0; reg < 4; ++reg) {
      const int m = (int)m0 + w0 * 64 + mr * 16 + lg * 4 + reg;
      const int bb = m / 59, tok = m - bb * 59;
      float* dst = (tok >= P)
          ? x_out + (size_t)(bb * NWTOK + tok - P) * 384
          : pbuf + (size_t)(bb * P + tok) * 384;
#pragma unroll
      for (int nc = 0; nc < 4; ++nc)
        dst[nn[nc]] = acc[mr][nc][reg] + bias[nc];
    }
}

// ---------------------------------------------------------------------------
// prompts_out = mean over 64 windows
// ---------------------------------------------------------------------------
__global__ __launch_bounds__(256) void reduce_prompts_kernel(
    const float* __restrict__ pbuf, float* __restrict__ po) {
  const int o = blockIdx.x * 256 + threadIdx.x;  // < 32*10*384
  const int b0 = o / 3840;
  const int rem = o - b0 * 3840;
  const float* base = pbuf + (size_t)b0 * 64 * 3840 + rem;
  float s = 0.f;
#pragma unroll 8
  for (int w = 0; w < 64; ++w) s += base[(size_t)w * 3840];
  po[o] = s * (1.f / 64.f);
}

extern "C" void kernel_launch(void* const* d_in, const int* in_sizes, int n_in,
                              void* d_out, int out_size, void* d_ws, size_t ws_size,
                              hipStream_t stream) {
  const float* x          = (const float*)d_in[0];
  const float* spa        = (const float*)d_in[1];
  const float* mask       = (const float*)d_in[2];
  const float* bias_table = (const float*)d_in[3];
  const float* w_qkv      = (const float*)d_in[4];
  const float* b_qkv      = (const float*)d_in[5];
  const float* w_proj     = (const float*)d_in[6];
  const float* b_proj     = (const float*)d_in[7];
  float* out = (float*)d_out;

  // ws layout (bytes):
  // [0, 92798976)            xc_bf  (bf16 120832x384)  -- later reused as attn_bf
  // [92798976, 371195904)    qkvw   (bf16 120832x1152, head-chunked)
  // [371195904, 372080640)   wqkv_bf
  // [372080640, 372375552)   wproj_bf
  // [372375552, 403832832)   pbuf   (f32 2048*10*384)
  unsigned short* xc_bf    = (unsigned short*)d_ws;
  unsigned short* attn_bf  = xc_bf;  // alias: xc consumed before attn writes
  unsigned short* qkvw     = (unsigned short*)((char*)d_ws + 92798976ULL);
  unsigned short* wqkv_bf  = (unsigned short*)((char*)d_ws + 371195904ULL);
  unsigned short* wproj_bf = (unsigned short*)((char*)d_ws + 372080640ULL);
  float*          pbuf     = (float*)((char*)d_ws + 372375552ULL);

  convert_w_kernel<<<216, 256, 0, stream>>>(w_qkv, wqkv_bf);
  convert_w_kernel<<<72, 256, 0, stream>>>(w_proj, wproj_bf);
  gather_x_kernel<<<22656, 256, 0, stream>>>(x, spa, xc_bf);
  gemm_qkv_kernel<<<dim3(9, 944), 256, 0, stream>>>(xc_bf, wqkv_bf, b_qkv, qkvw);
  attn_kernel<<<2048 * HEADS, 256, 0, stream>>>(qkvw, mask, bias_table,
                                                out + AW_OFF, attn_bf);
  gemm_proj_kernel<<<dim3(3, 944), 256, 0, stream>>>(attn_bf, wproj_bf, b_proj,
                                                     out, pbuf);
  reduce_prompts_kernel<<<480, 256, 0, stream>>>(pbuf, out + PO_OFF);
}

// Round 5
// 604.408 us; speedup vs baseline: 6.5783x; 1.1928x over previous
//
#include <hip/hip_runtime.h>
#include <hip/hip_bf16.h>

#define P     10
#define NTOK  59
#define HEADS 12
#define NWTOK 49

#define AW_OFF 38535168   // x_out elems: 2048*49*384
#define PO_OFF 124096512  // + attn_weight elems

typedef __attribute__((ext_vector_type(8))) short short8;
typedef __attribute__((ext_vector_type(8))) unsigned short ushort8;
typedef __attribute__((ext_vector_type(4))) float floatx4;
typedef unsigned int uint_g __attribute__((address_space(1)));
typedef unsigned int uint_l __attribute__((address_space(3)));

__device__ __forceinline__ unsigned short f2b(float f) {
  unsigned u = __builtin_bit_cast(unsigned, f);
  u += 0x7fffu + ((u >> 16) & 1u);
  return (unsigned short)(u >> 16);
}

__device__ __forceinline__ void gll16(const void* g, void* l) {
  __builtin_amdgcn_global_load_lds((const uint_g*)g, (uint_l*)l, 16, 0, 0);
}

// ---------------------------------------------------------------------------
// convert f32 -> bf16 flat
// ---------------------------------------------------------------------------
__global__ __launch_bounds__(256) void convert_w_kernel(
    const float* __restrict__ w, unsigned short* __restrict__ wb) {
  const int i = (blockIdx.x * 256 + threadIdx.x) * 8;
  const float4 a = *(const float4*)(w + i);
  const float4 b = *(const float4*)(w + i + 4);
  ushort8 o;
  o[0] = f2b(a.x); o[1] = f2b(a.y); o[2] = f2b(a.z); o[3] = f2b(a.w);
  o[4] = f2b(b.x); o[5] = f2b(b.y); o[6] = f2b(b.z); o[7] = f2b(b.w);
  *(ushort8*)(wb + i) = o;
}

// ---------------------------------------------------------------------------
// combo[wnd][h][ti][tj] = bias_table[relidx(ti,tj)][h] + mask[wnd][ti][tj]
// ---------------------------------------------------------------------------
__global__ __launch_bounds__(256) void combo_kernel(
    const float* __restrict__ mask, const float* __restrict__ bias_table,
    float* __restrict__ combo) {
  const int bid = blockIdx.x;          // wnd*12 + h
  const int h = bid % HEADS, wnd = bid / HEADS;
  for (int e = threadIdx.x; e < 2401; e += 256) {
    const int ti = e / 49, tj = e - (e / 49) * 49;
    const int ai = ti / 7, aj = ti - ai * 7;
    const int bi = tj / 7, bj = tj - bi * 7;
    const int ridx = (ai - bi + 6) * 13 + (aj - bj + 6);
    combo[(size_t)bid * 2401 + e] =
        bias_table[ridx * HEADS + h] + mask[(size_t)wnd * 2401 + e];
  }
}

// ---------------------------------------------------------------------------
// gather xc (prompt-broadcast + x) -> bf16 [120832][384]
// ---------------------------------------------------------------------------
__global__ __launch_bounds__(256) void gather_x_kernel(
    const float* __restrict__ x, const float* __restrict__ spa,
    unsigned short* __restrict__ xc) {
  const int chunk = blockIdx.x * 256 + threadIdx.x;   // 5,799,936 total
  const int m = chunk / 48, kc = chunk - m * 48;
  const int b = m / 59, tok = m - b * 59;
  const float* src = (tok < P)
      ? spa + ((size_t)((b >> 6) * P + tok)) * 384 + kc * 8
      : x + ((size_t)(b * NWTOK + tok - P)) * 384 + kc * 8;
  const float4 v0 = ((const float4*)src)[0];
  const float4 v1 = ((const float4*)src)[1];
  ushort8 o;
  o[0] = f2b(v0.x); o[1] = f2b(v0.y); o[2] = f2b(v0.z); o[3] = f2b(v0.w);
  o[4] = f2b(v1.x); o[5] = f2b(v1.y); o[6] = f2b(v1.z); o[7] = f2b(v1.w);
  *(ushort8*)(xc + (size_t)m * 384 + kc * 8) = o;
}

// ---------------------------------------------------------------------------
// QKV GEMM (unchanged from passing round 4)
// ---------------------------------------------------------------------------
__global__ __launch_bounds__(256) void gemm_qkv_kernel(
    const unsigned short* __restrict__ A, const unsigned short* __restrict__ Bw,
    const float* __restrict__ b_qkv, unsigned short* __restrict__ qkvw) {
  __shared__ unsigned short Asw[8192];
  __shared__ unsigned short Bsw[8192];
  const int t = threadIdx.x;
  const int w = t >> 6, lane = t & 63;
  const int lr = lane & 15, lg = lane >> 4;
  const int w0 = w >> 1, w1 = w & 1;
  const size_t m0 = (size_t)blockIdx.y * 128;
  const int n0 = blockIdx.x * 128;
  const int srow = lane >> 3, cpos = lane & 7;

  floatx4 acc[4][4];
#pragma unroll
  for (int mr = 0; mr < 4; ++mr)
#pragma unroll
    for (int nc = 0; nc < 4; ++nc) acc[mr][nc] = (floatx4)0.f;

  for (int k0 = 0; k0 < 384; k0 += 64) {
#pragma unroll
    for (int i = 0; i < 4; ++i) {
      const int r = (w * 4 + i) * 8 + srow;
      const int c = cpos ^ (r & 7);
      gll16(A + (m0 + r) * 384 + k0 + c * 8, Asw + (w * 4 + i) * 512);
      gll16(Bw + (size_t)(n0 + r) * 384 + k0 + c * 8, Bsw + (w * 4 + i) * 512);
    }
    __syncthreads();
#pragma unroll
    for (int kh = 0; kh < 2; ++kh) {
      short8 af[4], bf[4];
#pragma unroll
      for (int mr = 0; mr < 4; ++mr) {
        const int r = w0 * 64 + mr * 16 + lr;
        af[mr] = *(const short8*)(Asw + r * 64 + (((kh * 4 + lg) ^ (r & 7)) * 8));
      }
#pragma unroll
      for (int nc = 0; nc < 4; ++nc) {
        const int r = w1 * 64 + nc * 16 + lr;
        bf[nc] = *(const short8*)(Bsw + r * 64 + (((kh * 4 + lg) ^ (r & 7)) * 8));
      }
#pragma unroll
      for (int mr = 0; mr < 4; ++mr)
#pragma unroll
        for (int nc = 0; nc < 4; ++nc)
          acc[mr][nc] = __builtin_amdgcn_mfma_f32_16x16x32_bf16(
              af[mr], bf[nc], acc[mr][nc], 0, 0, 0);
    }
    __syncthreads();
  }

  const int sec = blockIdx.x / 3;
  float bias[4]; int hh[4], dd[4];
#pragma unroll
  for (int nc = 0; nc < 4; ++nc) {
    const int n = n0 + w1 * 64 + nc * 16 + lr;
    bias[nc] = b_qkv[n];
    hh[nc] = (n >> 5) % 12;
    dd[nc] = n & 31;
  }
#pragma unroll
  for (int mr = 0; mr < 4; ++mr)
#pragma unroll
    for (int reg = 0; reg < 4; ++reg) {
      const int m = (int)m0 + w0 * 64 + mr * 16 + lg * 4 + reg;
      const int bb = m / 59, tok = m - bb * 59;
      const size_t base = (size_t)(bb * 3 + sec) * 12 * 1888 + (size_t)tok * 32;
#pragma unroll
      for (int nc = 0; nc < 4; ++nc)
        qkvw[base + (size_t)hh[nc] * 1888 + dd[nc]] =
            f2b(acc[mr][nc][reg] + bias[nc]);
    }
}

// ---------------------------------------------------------------------------
// attention: per (b,h), 4 waves. Swapped QK^T -> in-register softmax.
// ---------------------------------------------------------------------------
__global__ __launch_bounds__(256) void attn_kernel(
    const unsigned short* __restrict__ qkvw, const float* __restrict__ combo,
    float* __restrict__ aw_out, unsigned short* __restrict__ attn_bf) {
  __shared__ char lds[31872];
  float* S = (float*)lds;                               // [64][66] f32
  unsigned short* qs = (unsigned short*)(lds + 16896);  // [64][40]
  unsigned short* ks = (unsigned short*)(lds + 22016);  // [64][40]
  unsigned short* vt = (unsigned short*)(lds + 27136);  // [32][74] (V^T)
  unsigned short* Pm = (unsigned short*)(lds + 16896);  // [64][72] alias qs/ks

  const int blk = blockIdx.x;
  const int b = blk / HEADS, h = blk - b * HEADS;
  const int t = threadIdx.x;
  const int w = t >> 6, lane = t & 63, lr = lane & 15, lg = lane >> 4;

  const size_t qoff = ((size_t)(b * 3 + 0) * 12 + h) * 1888;
  const size_t koff = ((size_t)(b * 3 + 1) * 12 + h) * 1888;
  const size_t voff = ((size_t)(b * 3 + 2) * 12 + h) * 1888;

  if (t < 236) {
    const int row = t >> 2, dc = (t & 3) * 8;
    const ushort8 q8 = *(const ushort8*)(qkvw + qoff + t * 8);
    const ushort8 k8 = *(const ushort8*)(qkvw + koff + t * 8);
    const ushort8 v8 = *(const ushort8*)(qkvw + voff + t * 8);
    *(ushort8*)(qs + row * 40 + dc) = q8;
    *(ushort8*)(ks + row * 40 + dc) = k8;
#pragma unroll
    for (int j = 0; j < 8; ++j) vt[(dc + j) * 74 + row] = v8[j];
  } else {
    const int e = t - 236;  // zero vt token cols 59..63
#pragma unroll
    for (int jj = 0; jj < 8; ++jj) {
      const int f = e * 8 + jj;  // 0..159
      vt[(f / 5) * 74 + 59 + (f % 5)] = 0;
    }
  }
  __syncthreads();

  // S^T-fragment trick: mfma(K,Q) -> lane holds S[q=w*16+lr][k=nt*16+lg*4+reg]
  const short8 qa = *(const short8*)(qs + (w * 16 + lr) * 40 + lg * 8);
  const int q = w * 16 + lr;
  floatx4 sacc[4];
#pragma unroll
  for (int nt = 0; nt < 4; ++nt) {
    const short8 kb = *(const short8*)(ks + (nt * 16 + lr) * 40 + lg * 8);
    sacc[nt] = __builtin_amdgcn_mfma_f32_16x16x32_bf16(kb, qa, (floatx4)0.f, 0, 0, 0);
  }
#pragma unroll
  for (int nt = 0; nt < 4; ++nt)
#pragma unroll
    for (int reg = 0; reg < 4; ++reg)
      S[q * 66 + nt * 16 + lg * 4 + reg] = sacc[nt][reg];
  __syncthreads();

  // coalesced raw-S output
  float* aw = aw_out + (size_t)blk * (NTOK * NTOK);
  for (int idx = t; idx < NTOK * NTOK; idx += 256) {
    const int i = idx / 59, j = idx - i * 59;
    aw[idx] = S[i * 66 + j];
  }

  // in-register softmax over the lane-local row
  const float scale = 0.17677669529663687f;
  const float* comb = combo + (size_t)((b & 63) * HEADS + h) * 2401;
  float ev[4][4];
  float mx = -3.0e38f;
#pragma unroll
  for (int nt = 0; nt < 4; ++nt)
#pragma unroll
    for (int reg = 0; reg < 4; ++reg) {
      const int kk = nt * 16 + lg * 4 + reg;
      float v = -3.0e38f;
      if (q < NTOK && kk < NTOK) {
        const float cb = (q >= P && kk >= P) ? comb[(q - P) * 49 + (kk - P)] : 0.f;
        v = fmaf(sacc[nt][reg], scale, cb);
      }
      ev[nt][reg] = v;
      mx = fmaxf(mx, v);
    }
  mx = fmaxf(mx, __shfl_xor(mx, 16));
  mx = fmaxf(mx, __shfl_xor(mx, 32));
  float sm = 0.f;
#pragma unroll
  for (int nt = 0; nt < 4; ++nt)
#pragma unroll
    for (int reg = 0; reg < 4; ++reg) {
      const float e = __expf(ev[nt][reg] - mx);
      ev[nt][reg] = e;
      sm += e;
    }
  sm += __shfl_xor(sm, 16);
  sm += __shfl_xor(sm, 32);
  const float inv = 1.0f / sm;
#pragma unroll
  for (int nt = 0; nt < 4; ++nt) {
    uint2 uu;
    uu.x = (unsigned)f2b(ev[nt][0] * inv) | ((unsigned)f2b(ev[nt][1] * inv) << 16);
    uu.y = (unsigned)f2b(ev[nt][2] * inv) | ((unsigned)f2b(ev[nt][3] * inv) << 16);
    *(uint2*)(Pm + q * 72 + nt * 16 + lg * 4) = uu;
  }

  // O = P @ V (wave-local rows; Pm/vt deps wave-local -> no barrier)
  floatx4 oacc[2];
  oacc[0] = (floatx4)0.f; oacc[1] = (floatx4)0.f;
#pragma unroll
  for (int kk = 0; kk < 2; ++kk) {
    const short8 pa = *(const short8*)(Pm + (w * 16 + lr) * 72 + kk * 32 + lg * 8);
#pragma unroll
    for (int nt = 0; nt < 2; ++nt) {
      const short8 vb = *(const short8*)(vt + (nt * 16 + lr) * 74 + kk * 32 + lg * 8);
      oacc[nt] = __builtin_amdgcn_mfma_f32_16x16x32_bf16(pa, vb, oacc[nt], 0, 0, 0);
    }
  }
#pragma unroll
  for (int nt = 0; nt < 2; ++nt)
#pragma unroll
    for (int reg = 0; reg < 4; ++reg) {
      const int row = w * 16 + lg * 4 + reg;
      if (row < NTOK) {
        const int d = nt * 16 + lr;
        attn_bf[((size_t)(b * NTOK + row)) * 384 + h * 32 + d] = f2b(oacc[nt][reg]);
      }
    }
}

// ---------------------------------------------------------------------------
// proj GEMM (unchanged from passing round 4)
// ---------------------------------------------------------------------------
__global__ __launch_bounds__(256) void gemm_proj_kernel(
    const unsigned short* __restrict__ A, const unsigned short* __restrict__ Bw,
    const float* __restrict__ b_proj, float* __restrict__ x_out,
    float* __restrict__ pbuf) {
  __shared__ unsigned short Asw[8192];
  __shared__ unsigned short Bsw[8192];
  const int t = threadIdx.x;
  const int w = t >> 6, lane = t & 63;
  const int lr = lane & 15, lg = lane >> 4;
  const int w0 = w >> 1, w1 = w & 1;
  const size_t m0 = (size_t)blockIdx.y * 128;
  const int n0 = blockIdx.x * 128;
  const int srow = lane >> 3, cpos = lane & 7;

  floatx4 acc[4][4];
#pragma unroll
  for (int mr = 0; mr < 4; ++mr)
#pragma unroll
    for (int nc = 0; nc < 4; ++nc) acc[mr][nc] = (floatx4)0.f;

  for (int k0 = 0; k0 < 384; k0 += 64) {
#pragma unroll
    for (int i = 0; i < 4; ++i) {
      const int r = (w * 4 + i) * 8 + srow;
      const int c = cpos ^ (r & 7);
      gll16(A + (m0 + r) * 384 + k0 + c * 8, Asw + (w * 4 + i) * 512);
      gll16(Bw + (size_t)(n0 + r) * 384 + k0 + c * 8, Bsw + (w * 4 + i) * 512);
    }
    __syncthreads();
#pragma unroll
    for (int kh = 0; kh < 2; ++kh) {
      short8 af[4], bf[4];
#pragma unroll
      for (int mr = 0; mr < 4; ++mr) {
        const int r = w0 * 64 + mr * 16 + lr;
        af[mr] = *(const short8*)(Asw + r * 64 + (((kh * 4 + lg) ^ (r & 7)) * 8));
      }
#pragma unroll
      for (int nc = 0; nc < 4; ++nc) {
        const int r = w1 * 64 + nc * 16 + lr;
        bf[nc] = *(const short8*)(Bsw + r * 64 + (((kh * 4 + lg) ^ (r & 7)) * 8));
      }
#pragma unroll
      for (int mr = 0; mr < 4; ++mr)
#pragma unroll
        for (int nc = 0; nc < 4; ++nc)
          acc[mr][nc] = __builtin_amdgcn_mfma_f32_16x16x32_bf16(
              af[mr], bf[nc], acc[mr][nc], 0, 0, 0);
    }
    __syncthreads();
  }

  float bias[4]; int nn[4];
#pragma unroll
  for (int nc = 0; nc < 4; ++nc) {
    nn[nc] = n0 + w1 * 64 + nc * 16 + lr;
    bias[nc] = b_proj[nn[nc]];
  }
#pragma unroll
  for (int mr = 0; mr < 4; ++mr)
#pragma unroll
    for (int reg = 0; reg < 4; ++reg) {
      const int m = (int)m0 + w0 * 64 + mr * 16 + lg * 4 + reg;
      const int bb = m / 59, tok = m - bb * 59;
      float* dst = (tok >= P)
          ? x_out + (size_t)(bb * NWTOK + tok - P) * 384
          : pbuf + (size_t)(bb * P + tok) * 384;
#pragma unroll
      for (int nc = 0; nc < 4; ++nc)
        dst[nn[nc]] = acc[mr][nc][reg] + bias[nc];
    }
}

// ---------------------------------------------------------------------------
// prompts_out = mean over 64 windows
// ---------------------------------------------------------------------------
__global__ __launch_bounds__(256) void reduce_prompts_kernel(
    const float* __restrict__ pbuf, float* __restrict__ po) {
  const int o = blockIdx.x * 256 + threadIdx.x;  // < 32*10*384
  const int b0 = o / 3840;
  const int rem = o - b0 * 3840;
  const float* base = pbuf + (size_t)b0 * 64 * 3840 + rem;
  float s = 0.f;
#pragma unroll 8
  for (int w = 0; w < 64; ++w) s += base[(size_t)w * 3840];
  po[o] = s * (1.f / 64.f);
}

extern "C" void kernel_launch(void* const* d_in, const int* in_sizes, int n_in,
                              void* d_out, int out_size, void* d_ws, size_t ws_size,
                              hipStream_t stream) {
  const float* x          = (const float*)d_in[0];
  const float* spa        = (const float*)d_in[1];
  const float* mask       = (const float*)d_in[2];
  const float* bias_table = (const float*)d_in[3];
  const float* w_qkv      = (const float*)d_in[4];
  const float* b_qkv      = (const float*)d_in[5];
  const float* w_proj     = (const float*)d_in[6];
  const float* b_proj     = (const float*)d_in[7];
  float* out = (float*)d_out;

  // ws layout (bytes):
  // [0, 92798976)            xc_bf (bf16 120832x384) -- reused as attn_bf
  // [92798976, 371195904)    qkvw  (bf16 120832x1152, head-chunked)
  // [371195904, 372080640)   wqkv_bf
  // [372080640, 372375552)   wproj_bf
  // [372375552, 403832832)   pbuf  (f32 2048*10*384)
  // [403832832, 411209472)   combo (f32 64*12*49*49)
  unsigned short* xc_bf    = (unsigned short*)d_ws;
  unsigned short* attn_bf  = xc_bf;  // alias: xc consumed before attn writes
  unsigned short* qkvw     = (unsigned short*)((char*)d_ws + 92798976ULL);
  unsigned short* wqkv_bf  = (unsigned short*)((char*)d_ws + 371195904ULL);
  unsigned short* wproj_bf = (unsigned short*)((char*)d_ws + 372080640ULL);
  float*          pbuf     = (float*)((char*)d_ws + 372375552ULL);
  float*          combo    = (float*)((char*)d_ws + 403832832ULL);

  convert_w_kernel<<<216, 256, 0, stream>>>(w_qkv, wqkv_bf);
  convert_w_kernel<<<72, 256, 0, stream>>>(w_proj, wproj_bf);
  combo_kernel<<<768, 256, 0, stream>>>(mask, bias_table, combo);
  gather_x_kernel<<<22656, 256, 0, stream>>>(x, spa, xc_bf);
  gemm_qkv_kernel<<<dim3(9, 944), 256, 0, stream>>>(xc_bf, wqkv_bf, b_qkv, qkvw);
  attn_kernel<<<2048 * HEADS, 256, 0, stream>>>(qkvw, combo, out + AW_OFF, attn_bf);
  gemm_proj_kernel<<<dim3(3, 944), 256, 0, stream>>>(attn_bf, wproj_bf, b_proj,
                                                     out, pbuf);
  reduce_prompts_kernel<<<480, 256, 0, stream>>>(pbuf, out + PO_OFF);
}

// Round 6
// 594.147 us; speedup vs baseline: 6.6920x; 1.0173x over previous
//
#include <hip/hip_runtime.h>
#include <hip/hip_bf16.h>

#define P     10
#define NTOK  59
#define HEADS 12
#define NWTOK 49

#define AW_OFF 38535168   // frozen: verified by 4 passing rounds
#define PO_OFF 124096512  // frozen: verified by 4 passing rounds

typedef __attribute__((ext_vector_type(8))) short short8;
typedef __attribute__((ext_vector_type(8))) unsigned short ushort8;
typedef __attribute__((ext_vector_type(4))) float floatx4;
typedef float f4u __attribute__((ext_vector_type(4), aligned(4)));
typedef unsigned int uint_g __attribute__((address_space(1)));
typedef unsigned int uint_l __attribute__((address_space(3)));

__device__ __forceinline__ unsigned short f2b(float f) {
  unsigned u = __builtin_bit_cast(unsigned, f);
  u += 0x7fffu + ((u >> 16) & 1u);
  return (unsigned short)(u >> 16);
}

__device__ __forceinline__ void gll16(const void* g, void* l) {
  __builtin_amdgcn_global_load_lds((const uint_g*)g, (uint_l*)l, 16, 0, 0);
}

// ---------------------------------------------------------------------------
// convert f32 -> bf16 flat (grid sized exactly: n/8/256 blocks)
// ---------------------------------------------------------------------------
__global__ __launch_bounds__(256) void convert_w_kernel(
    const float* __restrict__ w, unsigned short* __restrict__ wb) {
  const int i = (blockIdx.x * 256 + threadIdx.x) * 8;
  const float4 a = *(const float4*)(w + i);
  const float4 b = *(const float4*)(w + i + 4);
  ushort8 o;
  o[0] = f2b(a.x); o[1] = f2b(a.y); o[2] = f2b(a.z); o[3] = f2b(a.w);
  o[4] = f2b(b.x); o[5] = f2b(b.y); o[6] = f2b(b.z); o[7] = f2b(b.w);
  *(ushort8*)(wb + i) = o;
}

// ---------------------------------------------------------------------------
// combo[wnd][h][ti][tj] = bias_table[relidx(ti,tj)][h] + mask[wnd][ti][tj]
// ---------------------------------------------------------------------------
__global__ __launch_bounds__(256) void combo_kernel(
    const float* __restrict__ mask, const float* __restrict__ bias_table,
    float* __restrict__ combo) {
  const int bid = blockIdx.x;          // wnd*12 + h
  const int h = bid % HEADS, wnd = bid / HEADS;
  for (int e = threadIdx.x; e < 2401; e += 256) {
    const int ti = e / 49, tj = e - (e / 49) * 49;
    const int ai = ti / 7, aj = ti - ai * 7;
    const int bi = tj / 7, bj = tj - bi * 7;
    const int ridx = (ai - bi + 6) * 13 + (aj - bj + 6);
    combo[(size_t)bid * 2401 + e] =
        bias_table[ridx * HEADS + h] + mask[(size_t)wnd * 2401 + e];
  }
}

// ---------------------------------------------------------------------------
// QKV GEMM: x-rows (784 blocks of 128) + prompt rows (3 blocks, 320 valid).
// BM=BN=128, BK=64, 4 waves; global_load_lds w/ XOR-swizzled source.
// out: qkx[(b*3+sec)*12+h][tok49][32], qkp[(b0*3+sec)*12+h][tok10][32]
// ---------------------------------------------------------------------------
__global__ __launch_bounds__(256) void gemm_qkv_kernel(
    const unsigned short* __restrict__ xb, const unsigned short* __restrict__ xp,
    const unsigned short* __restrict__ Bw, const float* __restrict__ b_qkv,
    unsigned short* __restrict__ qkx, unsigned short* __restrict__ qkp) {
  __shared__ unsigned short Asw[8192];
  __shared__ unsigned short Bsw[8192];
  const int t = threadIdx.x;
  const int w = t >> 6, lane = t & 63;
  const int lr = lane & 15, lg = lane >> 4;
  const int w0 = w >> 1, w1 = w & 1;
  const int by = blockIdx.y;
  const bool isP = by >= 784;
  const int n0 = blockIdx.x * 128;
  const int srow = lane >> 3, cpos = lane & 7;

  floatx4 acc[4][4];
#pragma unroll
  for (int mr = 0; mr < 4; ++mr)
#pragma unroll
    for (int nc = 0; nc < 4; ++nc) acc[mr][nc] = (floatx4)0.f;

  for (int k0 = 0; k0 < 384; k0 += 64) {
#pragma unroll
    for (int i = 0; i < 4; ++i) {
      const int r = (w * 4 + i) * 8 + srow;
      const int c = cpos ^ (r & 7);
      const unsigned short* asrc;
      if (!isP) {
        asrc = xb + (size_t)(by * 128 + r) * 384 + k0 + c * 8;
      } else {
        int mp = (by - 784) * 128 + r;
        if (mp > 319) mp = 319;
        asrc = xp + (size_t)mp * 384 + k0 + c * 8;
      }
      gll16(asrc, Asw + (w * 4 + i) * 512);
      gll16(Bw + (size_t)(n0 + r) * 384 + k0 + c * 8, Bsw + (w * 4 + i) * 512);
    }
    __syncthreads();
#pragma unroll
    for (int kh = 0; kh < 2; ++kh) {
      short8 af[4], bf[4];
#pragma unroll
      for (int mr = 0; mr < 4; ++mr) {
        const int r = w0 * 64 + mr * 16 + lr;
        af[mr] = *(const short8*)(Asw + r * 64 + (((kh * 4 + lg) ^ (r & 7)) * 8));
      }
#pragma unroll
      for (int nc = 0; nc < 4; ++nc) {
        const int r = w1 * 64 + nc * 16 + lr;
        bf[nc] = *(const short8*)(Bsw + r * 64 + (((kh * 4 + lg) ^ (r & 7)) * 8));
      }
#pragma unroll
      for (int mr = 0; mr < 4; ++mr)
#pragma unroll
        for (int nc = 0; nc < 4; ++nc)
          acc[mr][nc] = __builtin_amdgcn_mfma_f32_16x16x32_bf16(
              af[mr], bf[nc], acc[mr][nc], 0, 0, 0);
    }
    __syncthreads();
  }

  const int sec = blockIdx.x / 3;
  float bias[4]; int hh[4], dd[4];
#pragma unroll
  for (int nc = 0; nc < 4; ++nc) {
    const int n = n0 + w1 * 64 + nc * 16 + lr;
    bias[nc] = b_qkv[n];
    hh[nc] = (n >> 5) % 12;
    dd[nc] = n & 31;
  }
#pragma unroll
  for (int mr = 0; mr < 4; ++mr)
#pragma unroll
    for (int reg = 0; reg < 4; ++reg) {
      const int rloc = w0 * 64 + mr * 16 + lg * 4 + reg;
      if (!isP) {
        const int m = by * 128 + rloc;
        const int bb = m / 49, tok = m - bb * 49;
        const size_t base = (size_t)(bb * 3 + sec) * 12 * 1568 + (size_t)tok * 32;
#pragma unroll
        for (int nc = 0; nc < 4; ++nc)
          qkx[base + (size_t)hh[nc] * 1568 + dd[nc]] =
              f2b(acc[mr][nc][reg] + bias[nc]);
      } else {
        const int mp = (by - 784) * 128 + rloc;
        if (mp < 320) {
          const int b0 = mp / 10, ptok = mp - b0 * 10;
          const size_t base = (size_t)(b0 * 3 + sec) * 12 * 320 + (size_t)ptok * 32;
#pragma unroll
          for (int nc = 0; nc < 4; ++nc)
            qkp[base + (size_t)hh[nc] * 320 + dd[nc]] =
                f2b(acc[mr][nc][reg] + bias[nc]);
        }
      }
    }
}

// ---------------------------------------------------------------------------
// attention: per (b,h), 4 waves. Swapped QK^T -> in-reg softmax,
// direct-reg aw stores, packed attn_bf stores. LDS 14976 B.
// ---------------------------------------------------------------------------
__global__ __launch_bounds__(256) void attn_kernel(
    const unsigned short* __restrict__ qkx, const unsigned short* __restrict__ qkp,
    const float* __restrict__ combo, float* __restrict__ aw_out,
    unsigned short* __restrict__ attn_bf) {
  __shared__ char lds[14976];
  unsigned short* qs = (unsigned short*)(lds);          // [64][40]
  unsigned short* ks = (unsigned short*)(lds + 5120);   // [64][40]
  unsigned short* vt = (unsigned short*)(lds + 10240);  // [32][74] (V^T)
  unsigned short* Pm = (unsigned short*)(lds);          // [64][72], alias qs/ks

  const int blk = blockIdx.x;
  const int b = blk / HEADS, h = blk - b * HEADS;
  const int t = threadIdx.x;
  const int w = t >> 6, lane = t & 63, lr = lane & 15, lg = lane >> 4;

  // ---- stage q/k/v ----
  if (t < 236) {
    const int row = t >> 2, dc = (t & 3) * 8;
    ushort8 q8, k8, v8;
    if (row < P) {
      const size_t base =
          ((size_t)((b >> 6) * 3) * 12 + h) * 320 + row * 32 + dc;
      q8 = *(const ushort8*)(qkp + base);
      k8 = *(const ushort8*)(qkp + base + 12 * 320);
      v8 = *(const ushort8*)(qkp + base + 24 * 320);
    } else {
      const size_t base =
          ((size_t)(b * 3) * 12 + h) * 1568 + (row - P) * 32 + dc;
      q8 = *(const ushort8*)(qkx + base);
      k8 = *(const ushort8*)(qkx + base + 12 * 1568);
      v8 = *(const ushort8*)(qkx + base + 24 * 1568);
    }
    *(ushort8*)(qs + row * 40 + dc) = q8;
    *(ushort8*)(ks + row * 40 + dc) = k8;
#pragma unroll
    for (int j = 0; j < 8; ++j) vt[(dc + j) * 74 + row] = v8[j];
  } else {
    const int e = t - 236;  // zero vt token cols 59..63
#pragma unroll
    for (int jj = 0; jj < 8; ++jj) {
      const int f = e * 8 + jj;  // 0..159
      vt[(f / 5) * 74 + 59 + (f % 5)] = 0;
    }
  }
  __syncthreads();

  // ---- S^T trick: mfma(K,Q) -> lane holds S[q][kk], q=w*16+lr ----
  const int q = w * 16 + lr;
  const short8 qa = *(const short8*)(qs + q * 40 + lg * 8);
  floatx4 sacc[4];
#pragma unroll
  for (int nt = 0; nt < 4; ++nt) {
    const short8 kb = *(const short8*)(ks + (nt * 16 + lr) * 40 + lg * 8);
    sacc[nt] = __builtin_amdgcn_mfma_f32_16x16x32_bf16(kb, qa, (floatx4)0.f, 0, 0, 0);
  }

  // ---- raw S straight from registers (16 rows x 64B per inst) ----
  if (q < NTOK) {
    float* rowp = aw_out + (size_t)blk * 3481 + q * 59;
#pragma unroll
    for (int nt = 0; nt < 3; ++nt)
      *(f4u*)(rowp + nt * 16 + lg * 4) = __builtin_bit_cast(f4u, sacc[nt]);
    if (lg < 2) {
      *(f4u*)(rowp + 48 + lg * 4) = __builtin_bit_cast(f4u, sacc[3]);
    } else if (lg == 2) {
      rowp[56] = sacc[3][0];
      rowp[57] = sacc[3][1];
      rowp[58] = sacc[3][2];
    }
  }

  // ---- in-register softmax over the lane-local row ----
  const float scale = 0.17677669529663687f;
  const float* comb = combo + (size_t)((b & 63) * HEADS + h) * 2401;
  float ev[4][4];
  float mx = -3.0e38f;
#pragma unroll
  for (int nt = 0; nt < 4; ++nt)
#pragma unroll
    for (int reg = 0; reg < 4; ++reg) {
      const int kk = nt * 16 + lg * 4 + reg;
      float v = -3.0e38f;
      if (q < NTOK && kk < NTOK) {
        const float cb = (q >= P && kk >= P) ? comb[(q - P) * 49 + (kk - P)] : 0.f;
        v = fmaf(sacc[nt][reg], scale, cb);
      }
      ev[nt][reg] = v;
      mx = fmaxf(mx, v);
    }
  mx = fmaxf(mx, __shfl_xor(mx, 16));
  mx = fmaxf(mx, __shfl_xor(mx, 32));
  float sm = 0.f;
#pragma unroll
  for (int nt = 0; nt < 4; ++nt)
#pragma unroll
    for (int reg = 0; reg < 4; ++reg) {
      const float e = __expf(ev[nt][reg] - mx);
      ev[nt][reg] = e;
      sm += e;
    }
  sm += __shfl_xor(sm, 16);
  sm += __shfl_xor(sm, 32);
  const float inv = 1.0f / sm;

  // Pm aliases qs/ks: wait until all waves finished their kb reads
  __syncthreads();
#pragma unroll
  for (int nt = 0; nt < 4; ++nt) {
    uint2 uu;
    uu.x = (unsigned)f2b(ev[nt][0] * inv) | ((unsigned)f2b(ev[nt][1] * inv) << 16);
    uu.y = (unsigned)f2b(ev[nt][2] * inv) | ((unsigned)f2b(ev[nt][3] * inv) << 16);
    *(uint2*)(Pm + q * 72 + nt * 16 + lg * 4) = uu;
  }

  // ---- O = P @ V (all Pm/vt deps wave-local; LDS ops in-order per wave) ----
  floatx4 oacc[2];
  oacc[0] = (floatx4)0.f; oacc[1] = (floatx4)0.f;
#pragma unroll
  for (int kk = 0; kk < 2; ++kk) {
    const short8 pa = *(const short8*)(Pm + (w * 16 + lr) * 72 + kk * 32 + lg * 8);
#pragma unroll
    for (int nt = 0; nt < 2; ++nt) {
      const short8 vb = *(const short8*)(vt + (nt * 16 + lr) * 74 + kk * 32 + lg * 8);
      oacc[nt] = __builtin_amdgcn_mfma_f32_16x16x32_bf16(pa, vb, oacc[nt], 0, 0, 0);
    }
  }

  // ---- pack O rows in own-wave LDS slice (stride 40), store 16B/lane ----
  unsigned short* wb = Pm + w * 1152;  // own wave's 2304B slice, reused
#pragma unroll
  for (int nt = 0; nt < 2; ++nt)
#pragma unroll
    for (int reg = 0; reg < 4; ++reg)
      wb[(lg * 4 + reg) * 40 + nt * 16 + lr] = f2b(oacc[nt][reg]);
  const int rr = lane >> 2, c8 = (lane & 3) * 8;
  const int row = w * 16 + rr;
  if (row < NTOK) {
    const ushort8 ov = *(const ushort8*)(wb + rr * 40 + c8);
    *(ushort8*)(attn_bf + ((size_t)(b * NTOK + row)) * 384 + h * 32 + c8) = ov;
  }
}

// ---------------------------------------------------------------------------
// proj GEMM: [120832][384] = attn_bf @ wproj_bf^T (+bias), f32 routed out.
// ---------------------------------------------------------------------------
__global__ __launch_bounds__(256) void gemm_proj_kernel(
    const unsigned short* __restrict__ A, const unsigned short* __restrict__ Bw,
    const float* __restrict__ b_proj, float* __restrict__ x_out,
    float* __restrict__ pbuf) {
  __shared__ unsigned short Asw[8192];
  __shared__ unsigned short Bsw[8192];
  const int t = threadIdx.x;
  const int w = t >> 6, lane = t & 63;
  const int lr = lane & 15, lg = lane >> 4;
  const int w0 = w >> 1, w1 = w & 1;
  const size_t m0 = (size_t)blockIdx.y * 128;
  const int n0 = blockIdx.x * 128;
  const int srow = lane >> 3, cpos = lane & 7;

  floatx4 acc[4][4];
#pragma unroll
  for (int mr = 0; mr < 4; ++mr)
#pragma unroll
    for (int nc = 0; nc < 4; ++nc) acc[mr][nc] = (floatx4)0.f;

  for (int k0 = 0; k0 < 384; k0 += 64) {
#pragma unroll
    for (int i = 0; i < 4; ++i) {
      const int r = (w * 4 + i) * 8 + srow;
      const int c = cpos ^ (r & 7);
      gll16(A + (m0 + r) * 384 + k0 + c * 8, Asw + (w * 4 + i) * 512);
      gll16(Bw + (size_t)(n0 + r) * 384 + k0 + c * 8, Bsw + (w * 4 + i) * 512);
    }
    __syncthreads();
#pragma unroll
    for (int kh = 0; kh < 2; ++kh) {
      short8 af[4], bf[4];
#pragma unroll
      for (int mr = 0; mr < 4; ++mr) {
        const int r = w0 * 64 + mr * 16 + lr;
        af[mr] = *(const short8*)(Asw + r * 64 + (((kh * 4 + lg) ^ (r & 7)) * 8));
      }
#pragma unroll
      for (int nc = 0; nc < 4; ++nc) {
        const int r = w1 * 64 + nc * 16 + lr;
        bf[nc] = *(const short8*)(Bsw + r * 64 + (((kh * 4 + lg) ^ (r & 7)) * 8));
      }
#pragma unroll
      for (int mr = 0; mr < 4; ++mr)
#pragma unroll
        for (int nc = 0; nc < 4; ++nc)
          acc[mr][nc] = __builtin_amdgcn_mfma_f32_16x16x32_bf16(
              af[mr], bf[nc], acc[mr][nc], 0, 0, 0);
    }
    __syncthreads();
  }

  float bias[4]; int nn[4];
#pragma unroll
  for (int nc = 0; nc < 4; ++nc) {
    nn[nc] = n0 + w1 * 64 + nc * 16 + lr;
    bias[nc] = b_proj[nn[nc]];
  }
#pragma unroll
  for (int mr = 0; mr < 4; ++mr)
#pragma unroll
    for (int reg = 0; reg < 4; ++reg) {
      const int m = (int)m0 + w0 * 64 + mr * 16 + lg * 4 + reg;
      const int bb = m / 59, tok = m - bb * 59;
      float* dst = (tok >= P)
          ? x_out + (size_t)(bb * NWTOK + tok - P) * 384
          : pbuf + (size_t)(bb * P + tok) * 384;
#pragma unroll
      for (int nc = 0; nc < 4; ++nc)
        dst[nn[nc]] = acc[mr][nc][reg] + bias[nc];
    }
}

// ---------------------------------------------------------------------------
// prompts_out = mean over 64 windows
// ---------------------------------------------------------------------------
__global__ __launch_bounds__(256) void reduce_prompts_kernel(
    const float* __restrict__ pbuf, float* __restrict__ po) {
  const int o = blockIdx.x * 256 + threadIdx.x;  // < 32*10*384
  const int b0 = o / 3840;
  const int rem = o - b0 * 3840;
  const float* base = pbuf + (size_t)b0 * 64 * 3840 + rem;
  float s = 0.f;
#pragma unroll 8
  for (int w = 0; w < 64; ++w) s += base[(size_t)w * 3840];
  po[o] = s * (1.f / 64.f);
}

extern "C" void kernel_launch(void* const* d_in, const int* in_sizes, int n_in,
                              void* d_out, int out_size, void* d_ws, size_t ws_size,
                              hipStream_t stream) {
  const float* x          = (const float*)d_in[0];
  const float* spa        = (const float*)d_in[1];
  const float* mask       = (const float*)d_in[2];
  const float* bias_table = (const float*)d_in[3];
  const float* w_qkv      = (const float*)d_in[4];
  const float* b_qkv      = (const float*)d_in[5];
  const float* w_proj     = (const float*)d_in[6];
  const float* b_proj     = (const float*)d_in[7];
  float* out = (float*)d_out;

  // ws layout (bytes):
  // [0, 77070336)            x_bf  (bf16 100352x384)   } overwritten by
  // [77070336, 77316096)     xp_bf (bf16 320x384)      } attn_bf after
  // [77316096, 78200832)     wqkv_bf                   } gemm_qkv done
  // [0, 92798976)            attn_bf (bf16 120832x384)
  // [92798976, 324009984)    qkx (bf16 100352x1152, head-chunked)
  // [324009984, 324747264)   qkp (bf16 320x1152, head-chunked)
  // [324747264, 325042176)   wproj_bf
  // [325042176, 356499456)   pbuf  (f32 2048*10*384)
  // [356499456, 363876352)   combo (f32 64*12*49*49)
  unsigned short* x_bf     = (unsigned short*)d_ws;
  unsigned short* attn_bf  = (unsigned short*)d_ws;
  unsigned short* xp_bf    = (unsigned short*)((char*)d_ws + 77070336ULL);
  unsigned short* wqkv_bf  = (unsigned short*)((char*)d_ws + 77316096ULL);
  unsigned short* qkx      = (unsigned short*)((char*)d_ws + 92798976ULL);
  unsigned short* qkp      = (unsigned short*)((char*)d_ws + 324009984ULL);
  unsigned short* wproj_bf = (unsigned short*)((char*)d_ws + 324747264ULL);
  float*          pbuf     = (float*)((char*)d_ws + 325042176ULL);
  float*          combo    = (float*)((char*)d_ws + 356499456ULL);

  convert_w_kernel<<<18816, 256, 0, stream>>>(x, x_bf);
  convert_w_kernel<<<60, 256, 0, stream>>>(spa, xp_bf);
  convert_w_kernel<<<216, 256, 0, stream>>>(w_qkv, wqkv_bf);
  convert_w_kernel<<<72, 256, 0, stream>>>(w_proj, wproj_bf);
  combo_kernel<<<768, 256, 0, stream>>>(mask, bias_table, combo);
  gemm_qkv_kernel<<<dim3(9, 787), 256, 0, stream>>>(x_bf, xp_bf, wqkv_bf, b_qkv,
                                                    qkx, qkp);
  attn_kernel<<<2048 * HEADS, 256, 0, stream>>>(qkx, qkp, combo, out + AW_OFF,
                                                attn_bf);
  gemm_proj_kernel<<<dim3(3, 944), 256, 0, stream>>>(attn_bf, wproj_bf, b_proj,
                                                     out, pbuf);
  reduce_prompts_kernel<<<480, 256, 0, stream>>>(pbuf, out + PO_OFF);
}